// Round 9
// baseline (187.018 us; speedup 1.0000x reference)
//
#include <hip/hip_runtime.h>
#include <hip/hip_bf16.h>

// HET relational attention layer.
//  K1 build_wextT : W_ext in FRAGMENT-MAJOR layout -> every gemm B-frag load is contiguous 1KB.
//  K2 gemm_direct : stage A f32->bf16 into XOR-swizzled LDS, MFMA, C via swizzled LDS ->
//                   coalesced 1KB stores. projR layout [rel][node][64].
//  CSR build      : bucketed (zero/count/scan/bucket_scatter/exact_place).
//                   exact_place now precomputes per-edge indices: rec_elr = s*64+r*4
//                   (elr float4 index; r*4 = rec_elr&63 for er) and rec_pidx =
//                   r*NN*64+s*64 (projR element index) -> agg inner loop is add-only.
//  K_agg          : 1 wave per dst node. Fast path deg<=64: pass A = exp once per edge
//                   -> LDS; pass B = PAIRED edges (half-wave per edge, uint=2 bf16/lane,
//                   shfl_xor(32) exchange) -> 0.5 VMEM inst/edge, ~7 VALU/edge.

#define NN 100000
#define NNP 100096            // 782*128
#define NE 1600000
#define NH 4
#define INF_ 128
#define DH 16
#define NCOL 576
#define LEAKY 0.2f
#define NBUCK 391
#define BSHIFT 8
#define CHUNK 4096

typedef __hip_bfloat16 bf16;
typedef __attribute__((ext_vector_type(8))) short bf16x8;
typedef __attribute__((ext_vector_type(4))) short bf16x4;
typedef __attribute__((ext_vector_type(4))) float f32x4;

static __device__ __forceinline__ short f2bs(float x) {
    bf16 b = __float2bfloat16(x);
    return *reinterpret_cast<short*>(&b);
}
static __device__ __forceinline__ float bflo(unsigned u) { return __uint_as_float(u << 16); }
static __device__ __forceinline__ float bfhi(unsigned u) { return __uint_as_float(u & 0xffff0000u); }

// Fragment-major W: for (cb,ks,ct,lane=g*16+r,e): col = cb*64+ct*16+r, k = ks*32+g*8+e.
__global__ void build_wextT(const float* __restrict__ W, const float* __restrict__ al,
                            const float* __restrict__ ar, short* __restrict__ wxt2) {
    int idx = blockIdx.x * 256 + threadIdx.x;
    if (idx >= NCOL * INF_) return;
    int e = idx & 7, lane = (idx >> 3) & 63, ct = (idx >> 9) & 3, ks = (idx >> 11) & 3, cb = idx >> 13;
    int g = lane >> 4, r = lane & 15;
    int c = cb * 64 + ct * 16 + r;
    int k = ks * 32 + g * 8 + e;
    float v;
    if (c < 512) {
        int rr = c >> 6, rem = c & 63, h = rem >> 4, d = rem & 15;
        v = W[((rr * NH + h) * INF_ + k) * DH + d];
    } else {
        int rh = c - 512;
        const float* a = al;
        if (rh >= 32) { rh -= 32; a = ar; }
        int rr = rh >> 2, h = rh & 3;
        const float* wp = &W[((rr * NH + h) * INF_ + k) * DH];
        const float* ap = &a[(rr * NH + h) * DH];
        float s = 0.f;
        #pragma unroll
        for (int d = 0; d < DH; ++d) s += wp[d] * ap[d];
        v = s;
    }
    wxt2[idx] = f2bs(v);
}

// Block = 4 waves, 128 rows, all 576 cols. All VMEM contiguous.
__global__ __launch_bounds__(256) void gemm_direct(
    const float* __restrict__ A, const short* __restrict__ WxT2,
    bf16* __restrict__ projR, float* __restrict__ elr) {
    __shared__ short As[16384];          // 32 KB: A-tile (swizzled), later C-stage slices
    int t = threadIdx.x;
    int wv = t >> 6, lane = t & 63;
    int n0 = blockIdx.x * 128;
    int g = lane >> 4, r = lane & 15;

    #pragma unroll
    for (int j = 0; j < 8; ++j) {
        int i = j * 256 + t;
        int row = i >> 4, c8 = i & 15;
        int gr = n0 + row;
        bf16x8 v;
        if (gr < NN) {
            float4 f0 = *(const float4*)&A[gr * INF_ + c8 * 8];
            float4 f1 = *(const float4*)&A[gr * INF_ + c8 * 8 + 4];
            v[0] = f2bs(f0.x); v[1] = f2bs(f0.y); v[2] = f2bs(f0.z); v[3] = f2bs(f0.w);
            v[4] = f2bs(f1.x); v[5] = f2bs(f1.y); v[6] = f2bs(f1.z); v[7] = f2bs(f1.w);
        } else {
            v = (bf16x8)(short)0;
        }
        *(bf16x8*)&As[(row * 16 + (c8 ^ (row & 7))) * 8] = v;
    }
    __syncthreads();

    bf16x8 afr[2][4];
    #pragma unroll
    for (int nt = 0; nt < 2; ++nt) {
        int row = wv * 32 + nt * 16 + r;
        #pragma unroll
        for (int ks = 0; ks < 4; ++ks)
            afr[nt][ks] = *(const bf16x8*)&As[(row * 16 + ((ks * 4 + g) ^ (r & 7))) * 8];
    }
    __syncthreads();                      // A-tile dead; reuse as C-stage
    short* Csh = &As[wv * 4096];          // per-wave 8 KB slice
    float* Csf = (float*)Csh;
    int n0w = n0 + wv * 32;

    for (int cb = 0; cb < 9; ++cb) {
        f32x4 acc[2][4] = {};
        #pragma unroll
        for (int ks = 0; ks < 4; ++ks) {
            #pragma unroll
            for (int ct = 0; ct < 4; ++ct) {
                bf16x8 b = *(const bf16x8*)&WxT2[(((cb * 4 + ks) * 4 + ct) * 64 + lane) * 8];
                acc[0][ct] = __builtin_amdgcn_mfma_f32_16x16x32_bf16(b, afr[0][ks], acc[0][ct], 0, 0, 0);
                acc[1][ct] = __builtin_amdgcn_mfma_f32_16x16x32_bf16(b, afr[1][ks], acc[1][ct], 0, 0, 0);
            }
        }
        // lane(g,r), reg q: row = n0w + nt*16 + r, col = cb*64 + ct*16 + g*4 + q.
        if (cb < 8) {
            #pragma unroll
            for (int nt = 0; nt < 2; ++nt) {
                int rr = nt * 16 + r;
                #pragma unroll
                for (int ct = 0; ct < 4; ++ct) {
                    bf16x4 p;
                    p[0] = f2bs(acc[nt][ct][0]); p[1] = f2bs(acc[nt][ct][1]);
                    p[2] = f2bs(acc[nt][ct][2]); p[3] = f2bs(acc[nt][ct][3]);
                    *(bf16x4*)&Csh[rr * 64 + (((ct * 4 + g) ^ ((rr & 7) << 1)) << 2)] = p;
                }
            }
            __builtin_amdgcn_wave_barrier();
            size_t base = ((size_t)cb * NN + n0w) * 64;
            #pragma unroll
            for (int q = 0; q < 4; ++q) {
                int rr = (lane >> 3) + q * 8;
                if (n0w + rr < NN) {
                    bf16x8 vv = *(const bf16x8*)&Csh[rr * 64 + (((lane & 7) ^ (rr & 7)) << 3)];
                    *(bf16x8*)&((short*)projR)[base + q * 512 + lane * 8] = vv;
                }
            }
            __builtin_amdgcn_wave_barrier();
        } else {
            #pragma unroll
            for (int nt = 0; nt < 2; ++nt) {
                int rr = nt * 16 + r;
                #pragma unroll
                for (int ct = 0; ct < 4; ++ct)
                    *(f32x4*)&Csf[rr * 64 + (((ct * 4 + g) ^ ((rr & 7) << 1)) << 2)] = acc[nt][ct];
            }
            __builtin_amdgcn_wave_barrier();
            #pragma unroll
            for (int q = 0; q < 8; ++q) {
                int rr = (lane >> 4) + q * 4;
                if (n0w + rr < NN) {
                    f32x4 vv = *(const f32x4*)&Csf[rr * 64 + (((lane & 15) ^ ((rr & 7) << 1)) << 2)];
                    *(f32x4*)&elr[(size_t)n0w * 64 + q * 256 + lane * 4] = vv;
                }
            }
        }
    }
}

__global__ void zero_buckets(int* __restrict__ bucketCount) {
    int i = blockIdx.x * 256 + threadIdx.x;
    if (i < NBUCK) bucketCount[i] = 0;
}

__global__ __launch_bounds__(256) void bucket_count(const int* __restrict__ dst,
                                                    int* __restrict__ bucketCount) {
    __shared__ int hist[NBUCK];
    int t = threadIdx.x;
    for (int i = t; i < NBUCK; i += 256) hist[i] = 0;
    __syncthreads();
    int base = blockIdx.x * CHUNK;
    #pragma unroll
    for (int j = 0; j < CHUNK / 256; ++j) {
        int e = base + j * 256 + t;
        if (e < NE) atomicAdd(&hist[dst[e] >> BSHIFT], 1);
    }
    __syncthreads();
    for (int i = t; i < NBUCK; i += 256) {
        int v = hist[i];
        if (v) atomicAdd(&bucketCount[i], v);
    }
}

__global__ __launch_bounds__(256) void scan_buckets(const int* __restrict__ bucketCount,
                                                    int* __restrict__ bucketOff,
                                                    int* __restrict__ gCursor) {
    __shared__ int tsum[256];
    int t = threadIdx.x;
    int i0 = 2 * t, i1 = 2 * t + 1;
    int a = (i0 < NBUCK) ? bucketCount[i0] : 0;
    int b = (i1 < NBUCK) ? bucketCount[i1] : 0;
    int own = a + b;
    tsum[t] = own;
    __syncthreads();
    for (int st = 1; st < 256; st <<= 1) {
        int y = (t >= st) ? tsum[t - st] : 0;
        __syncthreads();
        tsum[t] += y;
        __syncthreads();
    }
    int excl = tsum[t] - own;
    if (i0 <= NBUCK) { bucketOff[i0] = excl; if (i0 < NBUCK) gCursor[i0] = excl; }
    if (i1 <= NBUCK) { bucketOff[i1] = excl + a; if (i1 < NBUCK) gCursor[i1] = excl + a; }
}

// rec32 = (dst&255)<<20 | (src*8+rel)
__global__ __launch_bounds__(256) void bucket_scatter(
    const int* __restrict__ src, const int* __restrict__ dst, const int* __restrict__ rel,
    int* __restrict__ gCursor, int* __restrict__ pairbuf) {
    __shared__ int hist[NBUCK];
    int t = threadIdx.x;
    for (int i = t; i < NBUCK; i += 256) hist[i] = 0;
    __syncthreads();
    int base = blockIdx.x * CHUNK;
    #pragma unroll
    for (int j = 0; j < CHUNK / 256; ++j) {
        int e = base + j * 256 + t;
        if (e < NE) atomicAdd(&hist[dst[e] >> BSHIFT], 1);
    }
    __syncthreads();
    for (int i = t; i < NBUCK; i += 256) {
        int v = hist[i];
        hist[i] = v ? atomicAdd(&gCursor[i], v) : 0;
    }
    __syncthreads();
    #pragma unroll
    for (int j = 0; j < CHUNK / 256; ++j) {
        int e = base + j * 256 + t;
        if (e < NE) {
            int d = dst[e];
            int b = d >> BSHIFT;
            int rec = ((d & 255) << 20) | (src[e] * 8 + rel[e]);
            int pos = atomicAdd(&hist[b], 1);
            pairbuf[pos] = rec;
        }
    }
}

__global__ __launch_bounds__(256) void exact_place(
    const int* __restrict__ bucketOff, const int* __restrict__ pairbuf,
    int* __restrict__ offsets, int* __restrict__ rec_elr, int* __restrict__ rec_pidx) {
    __shared__ int hist[256];
    __shared__ int tsum[256];
    int b = blockIdx.x, t = threadIdx.x;
    int start = bucketOff[b], cnt = bucketOff[b + 1] - start;
    hist[t] = 0;
    __syncthreads();
    for (int i = t; i < cnt; i += 256) atomicAdd(&hist[pairbuf[start + i] >> 20], 1);
    __syncthreads();
    int own = hist[t];
    tsum[t] = own;
    __syncthreads();
    for (int st = 1; st < 256; st <<= 1) {
        int y = (t >= st) ? tsum[t - st] : 0;
        __syncthreads();
        tsum[t] += y;
        __syncthreads();
    }
    int excl = start + tsum[t] - own;
    int node = b * 256 + t;
    if (node <= NN) offsets[node] = excl;
    __syncthreads();
    hist[t] = excl;
    __syncthreads();
    for (int i = t; i < cnt; i += 256) {
        int rec = pairbuf[start + i];
        int pos = atomicAdd(&hist[rec >> 20], 1);
        int sr = rec & 0xFFFFF;
        rec_elr[pos]  = (sr >> 3) * 64 + (sr & 7) * 4;            // elr float index
        rec_pidx[pos] = (sr & 7) * (NN * 64) + (sr >> 3) * 64;    // projR element index
    }
}

__global__ __launch_bounds__(256) void agg(
    const int* __restrict__ offsets, const int* __restrict__ rec_elr,
    const int* __restrict__ rec_pidx, const float* __restrict__ elr,
    const bf16* __restrict__ projR, const float* __restrict__ bias,
    float* __restrict__ out) {
    __shared__ float s_alpha[4][64][4];
    __shared__ int   s_pidx[4][64];
    __shared__ float s_er[4][32];
    int wv = threadIdx.x >> 6, lane = threadIdx.x & 63;
    int d = blockIdx.x * 4 + wv;
    if (d >= NN) return;
    int off = offsets[d], end = offsets[d + 1];
    int deg = end - off;

    if (lane < 32) s_er[wv][lane] = elr[d * 64 + 32 + lane];
    __builtin_amdgcn_wave_barrier();
    asm volatile("s_waitcnt lgkmcnt(0)" ::: "memory");

    if (deg == 0) {
        if (lane < 32) {
            float2 bb = *(const float2*)&bias[lane * 2];
            *(float2*)&out[d * 64 + lane * 2] = bb;
        }
    } else if (deg <= 64) {
        // pass A: one edge per lane; exp once, stash alpha + pidx in LDS
        int i = off + lane;
        float e0 = 0.f, e1 = 0.f, e2 = 0.f, e3 = 0.f;
        int pidx = 0;
        if (i < end) {
            int eidx = rec_elr[i];
            pidx = rec_pidx[i];
            float4 el4 = *(const float4*)&elr[eidx];
            int erb = eidx & 63;          // r*4
            float x;
            x = el4.x + s_er[wv][erb + 0]; x = x > 0.f ? x : LEAKY * x; e0 = __expf(x);
            x = el4.y + s_er[wv][erb + 1]; x = x > 0.f ? x : LEAKY * x; e1 = __expf(x);
            x = el4.z + s_er[wv][erb + 2]; x = x > 0.f ? x : LEAKY * x; e2 = __expf(x);
            x = el4.w + s_er[wv][erb + 3]; x = x > 0.f ? x : LEAKY * x; e3 = __expf(x);
        }
        s_pidx[wv][lane] = pidx;
        *(float4*)&s_alpha[wv][lane][0] = make_float4(e0, e1, e2, e3);
        __builtin_amdgcn_wave_barrier();
        asm volatile("s_waitcnt lgkmcnt(0)" ::: "memory");

        // pass B: paired edges. half-wave hl handles edge j+hl; lane covers cols 2c,2c+1.
        int col2 = (lane & 31) * 2;
        int hl = lane >> 5;
        int h2 = (lane & 31) >> 3;        // head of both cols
        float acc0 = 0.f, acc1 = 0.f, dsum = 0.f;
        int j = 0;
        for (; j + 8 <= deg; j += 8) {
            unsigned uu[4];
            #pragma unroll
            for (int p = 0; p < 4; ++p) {
                int myp = s_pidx[wv][j + 2 * p + hl];
                uu[p] = *(const unsigned*)&projR[myp + col2];
            }
            #pragma unroll
            for (int p = 0; p < 4; ++p) {
                float a_self = s_alpha[wv][j + 2 * p + hl][h2];
                float a_oth  = s_alpha[wv][j + 2 * p + 1 - hl][h2];
                unsigned uo = __shfl_xor((int)uu[p], 32);
                acc0 = fmaf(a_self, bflo(uu[p]), acc0);
                acc1 = fmaf(a_self, bfhi(uu[p]), acc1);
                acc0 = fmaf(a_oth, bflo(uo), acc0);
                acc1 = fmaf(a_oth, bfhi(uo), acc1);
                dsum += a_self + a_oth;
            }
        }
        for (; j + 2 <= deg; j += 2) {
            int myp = s_pidx[wv][j + hl];
            unsigned u = *(const unsigned*)&projR[myp + col2];
            float a_self = s_alpha[wv][j + hl][h2];
            float a_oth  = s_alpha[wv][j + 1 - hl][h2];
            unsigned uo = __shfl_xor((int)u, 32);
            acc0 = fmaf(a_self, bflo(u), acc0);
            acc1 = fmaf(a_self, bfhi(u), acc1);
            acc0 = fmaf(a_oth, bflo(uo), acc0);
            acc1 = fmaf(a_oth, bfhi(uo), acc1);
            dsum += a_self + a_oth;
        }
        if (j < deg) {                    // odd tail: both halves same edge (no shuffle)
            int myp = s_pidx[wv][j];
            unsigned u = *(const unsigned*)&projR[myp + col2];
            float a = s_alpha[wv][j][h2];
            acc0 = fmaf(a, bflo(u), acc0);
            acc1 = fmaf(a, bfhi(u), acc1);
            dsum += a;
        }
        if (lane < 32) {
            float inv = 1.0f / dsum;
            float2 bb = *(const float2*)&bias[col2];
            float2 o;
            o.x = acc0 * inv + bb.x;
            o.y = acc1 * inv + bb.y;
            *(float2*)&out[d * 64 + col2] = o;
        }
    } else {
        // slow path (deg > 64): two-pass recompute (rare)
        int c = lane, h = c >> 4;
        float dsum0 = 0.f, dsum1 = 0.f, dsum2 = 0.f, dsum3 = 0.f;
        for (int i = off + lane; i < end; i += 64) {
            int eidx = rec_elr[i];
            float4 el4 = *(const float4*)&elr[eidx];
            int erb = eidx & 63;
            float x;
            x = el4.x + s_er[wv][erb + 0]; x = x > 0.f ? x : LEAKY * x; dsum0 += __expf(x);
            x = el4.y + s_er[wv][erb + 1]; x = x > 0.f ? x : LEAKY * x; dsum1 += __expf(x);
            x = el4.z + s_er[wv][erb + 2]; x = x > 0.f ? x : LEAKY * x; dsum2 += __expf(x);
            x = el4.w + s_er[wv][erb + 3]; x = x > 0.f ? x : LEAKY * x; dsum3 += __expf(x);
        }
        #pragma unroll
        for (int m = 32; m; m >>= 1) {
            dsum0 += __shfl_xor(dsum0, m, 64);
            dsum1 += __shfl_xor(dsum1, m, 64);
            dsum2 += __shfl_xor(dsum2, m, 64);
            dsum3 += __shfl_xor(dsum3, m, 64);
        }
        float dh = (h == 0) ? dsum0 : (h == 1) ? dsum1 : (h == 2) ? dsum2 : dsum3;
        float rd = 1.0f / dh;
        float acc = 0.f;
        for (int i = off; i < end; ++i) {
            int eidx = rec_elr[i];        // wave-uniform -> broadcast
            int p = rec_pidx[i];
            float x = elr[eidx + h] + s_er[wv][(eidx & 63) + h];
            x = x > 0.f ? x : LEAKY * x;
            acc = fmaf(__expf(x) * rd, __bfloat162float(projR[p + c]), acc);
        }
        out[d * 64 + c] = acc + bias[c];
    }
}

extern "C" void kernel_launch(void* const* d_in, const int* in_sizes, int n_in,
                              void* d_out, int out_size, void* d_ws, size_t ws_size,
                              hipStream_t stream) {
    const float* inputs = (const float*)d_in[0];
    const float* convw  = (const float*)d_in[1];
    const float* attn_l = (const float*)d_in[2];
    const float* attn_r = (const float*)d_in[3];
    const float* h_bias = (const float*)d_in[4];
    const int*   src    = (const int*)d_in[5];
    const int*   dst    = (const int*)d_in[6];
    const int*   rel    = (const int*)d_in[7];
    float* out = (float*)d_out;

    char* ws = (char*)d_ws;
    size_t o = 0;
    bf16* projR = (bf16*)(ws + o);  o += 102400000ull;   // [8][NN][64]
    float* elr  = (float*)(ws + o); o += 25600000ull;
    short* wxt2 = (short*)(ws + o); o += 147456;
    int* offsets     = (int*)(ws + o); o += 400128;
    int* bucketCount = (int*)(ws + o); o += 1600;
    int* bucketOff   = (int*)(ws + o); o += 1600;
    int* gCursor     = (int*)(ws + o); o += 1600;
    int* pairbuf     = (int*)(ws + o); o += 6400000ull;
    int* rec_elr     = (int*)(ws + o); o += 6400000ull;
    int* rec_pidx    = (int*)(ws + o); o += 6400000ull;

    hipLaunchKernelGGL(build_wextT, dim3(288), dim3(256), 0, stream, convw, attn_l, attn_r, wxt2);
    hipLaunchKernelGGL(gemm_direct, dim3(NNP / 128), dim3(256), 0, stream, inputs, wxt2, projR, elr);
    hipLaunchKernelGGL(zero_buckets, dim3(2), dim3(256), 0, stream, bucketCount);
    hipLaunchKernelGGL(bucket_count, dim3(NBUCK), dim3(256), 0, stream, dst, bucketCount);
    hipLaunchKernelGGL(scan_buckets, dim3(1), dim3(256), 0, stream, bucketCount, bucketOff, gCursor);
    hipLaunchKernelGGL(bucket_scatter, dim3(NBUCK), dim3(256), 0, stream, src, dst, rel, gCursor, pairbuf);
    hipLaunchKernelGGL(exact_place, dim3(NBUCK), dim3(256), 0, stream, bucketOff, pairbuf, offsets, rec_elr, rec_pidx);
    hipLaunchKernelGGL(agg, dim3(25000), dim3(256), 0, stream, offsets, rec_elr, rec_pidx, elr, projR, h_bias, out);
}

// Round 10
// 176.971 us; speedup vs baseline: 1.0568x; 1.0568x over previous
//
#include <hip/hip_runtime.h>
#include <hip/hip_bf16.h>

// HET relational attention layer.
//  K1 build_wextT : W_ext fragment-major (every gemm B-frag load = contiguous 1KB);
//                   blocks >= 288 zero bucketCount (fused zero_buckets).
//  K2 gemm_direct : 512 threads / 8 waves, 16 rows/wave. Stage A f32->bf16 into
//                   XOR-swizzled LDS, MFMA (swapped operands), C via swizzled per-wave
//                   LDS slice -> coalesced 1KB stores. projR layout [rel][node][64].
//  CSR build      : bucket_count -> scan_buckets -> bucket_scatter -> exact_place.
//                   exact_place writes rec2 = int2{ elr_idx = s*64+r*4, pidx = r*NN*64+s*64 }.
//  K_agg          : 1 wave per dst node. Fast path deg<=64: pass A = one int2 load +
//                   exp once per edge -> LDS; pass B = paired edges (half-wave per edge,
//                   uint = 2 bf16 cols/lane, shfl_xor(32) exchange).

#define NN 100000
#define NNP 100096            // 782*128
#define NE 1600000
#define NH 4
#define INF_ 128
#define DH 16
#define NCOL 576
#define LEAKY 0.2f
#define NBUCK 391
#define BSHIFT 8
#define CHUNK 4096

typedef __hip_bfloat16 bf16;
typedef __attribute__((ext_vector_type(8))) short bf16x8;
typedef __attribute__((ext_vector_type(4))) short bf16x4;
typedef __attribute__((ext_vector_type(4))) float f32x4;

static __device__ __forceinline__ short f2bs(float x) {
    bf16 b = __float2bfloat16(x);
    return *reinterpret_cast<short*>(&b);
}
static __device__ __forceinline__ float bflo(unsigned u) { return __uint_as_float(u << 16); }
static __device__ __forceinline__ float bfhi(unsigned u) { return __uint_as_float(u & 0xffff0000u); }

// Fragment-major W: for (cb,ks,ct,lane=g*16+r,e): col = cb*64+ct*16+r, k = ks*32+g*8+e.
// Blocks 288..289: zero bucketCount (fused).
__global__ void build_wextT(const float* __restrict__ W, const float* __restrict__ al,
                            const float* __restrict__ ar, short* __restrict__ wxt2,
                            int* __restrict__ bucketCount) {
    if (blockIdx.x >= 288) {
        int i = (blockIdx.x - 288) * 256 + threadIdx.x;
        if (i < NBUCK) bucketCount[i] = 0;
        return;
    }
    int idx = blockIdx.x * 256 + threadIdx.x;
    int e = idx & 7, lane = (idx >> 3) & 63, ct = (idx >> 9) & 3, ks = (idx >> 11) & 3, cb = idx >> 13;
    int g = lane >> 4, r = lane & 15;
    int c = cb * 64 + ct * 16 + r;
    int k = ks * 32 + g * 8 + e;
    float v;
    if (c < 512) {
        int rr = c >> 6, rem = c & 63, h = rem >> 4, d = rem & 15;
        v = W[((rr * NH + h) * INF_ + k) * DH + d];
    } else {
        int rh = c - 512;
        const float* a = al;
        if (rh >= 32) { rh -= 32; a = ar; }
        int rr = rh >> 2, h = rh & 3;
        const float* wp = &W[((rr * NH + h) * INF_ + k) * DH];
        const float* ap = &a[(rr * NH + h) * DH];
        float s = 0.f;
        #pragma unroll
        for (int d = 0; d < DH; ++d) s += wp[d] * ap[d];
        v = s;
    }
    wxt2[idx] = f2bs(v);
}

// 512 threads = 8 waves; wave owns 16 rows; block covers 128 rows x all 576 cols.
__global__ __launch_bounds__(512) void gemm_direct(
    const float* __restrict__ A, const short* __restrict__ WxT2,
    bf16* __restrict__ projR, float* __restrict__ elr) {
    __shared__ short As[16384];          // 32 KB: A-tile (swizzled), later 8x 4KB C-slices
    int t = threadIdx.x;
    int wv = t >> 6, lane = t & 63;
    int n0 = blockIdx.x * 128;
    int g = lane >> 4, r = lane & 15;

    // Phase 1: stage A (coalesced f32 reads -> bf16 -> swizzled LDS). 2048 granules / 512.
    #pragma unroll
    for (int j = 0; j < 4; ++j) {
        int i = j * 512 + t;
        int row = i >> 4, c8 = i & 15;
        int gr = n0 + row;
        bf16x8 v;
        if (gr < NN) {
            float4 f0 = *(const float4*)&A[gr * INF_ + c8 * 8];
            float4 f1 = *(const float4*)&A[gr * INF_ + c8 * 8 + 4];
            v[0] = f2bs(f0.x); v[1] = f2bs(f0.y); v[2] = f2bs(f0.z); v[3] = f2bs(f0.w);
            v[4] = f2bs(f1.x); v[5] = f2bs(f1.y); v[6] = f2bs(f1.z); v[7] = f2bs(f1.w);
        } else {
            v = (bf16x8)(short)0;
        }
        *(bf16x8*)&As[(row * 16 + (c8 ^ (row & 7))) * 8] = v;
    }
    __syncthreads();

    // Phase 2: A fragments (one-time). row = wv*16+r; granule (ks*4+g)^(r&7).
    bf16x8 afr[4];
    {
        int row = wv * 16 + r;
        #pragma unroll
        for (int ks = 0; ks < 4; ++ks)
            afr[ks] = *(const bf16x8*)&As[(row * 16 + ((ks * 4 + g) ^ (r & 7))) * 8];
    }
    __syncthreads();                      // A-tile dead; reuse as C-stage
    short* Csh = &As[wv * 2048];          // per-wave 4 KB slice
    float* Csf = (float*)Csh;
    int n0w = n0 + wv * 16;

    for (int cb = 0; cb < 9; ++cb) {
        f32x4 acc[4] = {};
        #pragma unroll
        for (int ks = 0; ks < 4; ++ks) {
            #pragma unroll
            for (int ct = 0; ct < 4; ++ct) {
                bf16x8 b = *(const bf16x8*)&WxT2[(((cb * 4 + ks) * 4 + ct) * 64 + lane) * 8];
                acc[ct] = __builtin_amdgcn_mfma_f32_16x16x32_bf16(b, afr[ks], acc[ct], 0, 0, 0);
            }
        }
        // lane(g,r), reg q: row = n0w + r, col = cb*64 + ct*16 + g*4 + q.
        if (cb < 8) {
            int rr = r;
            #pragma unroll
            for (int ct = 0; ct < 4; ++ct) {
                bf16x4 p;
                p[0] = f2bs(acc[ct][0]); p[1] = f2bs(acc[ct][1]);
                p[2] = f2bs(acc[ct][2]); p[3] = f2bs(acc[ct][3]);
                *(bf16x4*)&Csh[rr * 64 + (((ct * 4 + g) ^ ((rr & 7) << 1)) << 2)] = p;
            }
            __builtin_amdgcn_wave_barrier();
            size_t base = ((size_t)cb * NN + n0w) * 64;
            #pragma unroll
            for (int q = 0; q < 2; ++q) {
                int r2 = (lane >> 3) + q * 8;
                if (n0w + r2 < NN) {
                    bf16x8 vv = *(const bf16x8*)&Csh[r2 * 64 + (((lane & 7) ^ (r2 & 7)) << 3)];
                    *(bf16x8*)&((short*)projR)[base + q * 512 + lane * 8] = vv;
                }
            }
            __builtin_amdgcn_wave_barrier();
        } else {
            int rr = r;
            #pragma unroll
            for (int ct = 0; ct < 4; ++ct)
                *(f32x4*)&Csf[rr * 64 + (((ct * 4 + g) ^ ((rr & 7) << 1)) << 2)] = acc[ct];
            __builtin_amdgcn_wave_barrier();
            #pragma unroll
            for (int q = 0; q < 4; ++q) {
                int r2 = (lane >> 4) + q * 4;
                if (n0w + r2 < NN) {
                    f32x4 vv = *(const f32x4*)&Csf[r2 * 64 + (((lane & 15) ^ ((r2 & 7) << 1)) << 2)];
                    *(f32x4*)&elr[(size_t)n0w * 64 + q * 256 + lane * 4] = vv;
                }
            }
        }
    }
}

__global__ __launch_bounds__(256) void bucket_count(const int* __restrict__ dst,
                                                    int* __restrict__ bucketCount) {
    __shared__ int hist[NBUCK];
    int t = threadIdx.x;
    for (int i = t; i < NBUCK; i += 256) hist[i] = 0;
    __syncthreads();
    int base = blockIdx.x * CHUNK;
    #pragma unroll
    for (int j = 0; j < CHUNK / 256; ++j) {
        int e = base + j * 256 + t;
        if (e < NE) atomicAdd(&hist[dst[e] >> BSHIFT], 1);
    }
    __syncthreads();
    for (int i = t; i < NBUCK; i += 256) {
        int v = hist[i];
        if (v) atomicAdd(&bucketCount[i], v);
    }
}

__global__ __launch_bounds__(256) void scan_buckets(const int* __restrict__ bucketCount,
                                                    int* __restrict__ bucketOff,
                                                    int* __restrict__ gCursor) {
    __shared__ int tsum[256];
    int t = threadIdx.x;
    int i0 = 2 * t, i1 = 2 * t + 1;
    int a = (i0 < NBUCK) ? bucketCount[i0] : 0;
    int b = (i1 < NBUCK) ? bucketCount[i1] : 0;
    int own = a + b;
    tsum[t] = own;
    __syncthreads();
    for (int st = 1; st < 256; st <<= 1) {
        int y = (t >= st) ? tsum[t - st] : 0;
        __syncthreads();
        tsum[t] += y;
        __syncthreads();
    }
    int excl = tsum[t] - own;
    if (i0 <= NBUCK) { bucketOff[i0] = excl; if (i0 < NBUCK) gCursor[i0] = excl; }
    if (i1 <= NBUCK) { bucketOff[i1] = excl + a; if (i1 < NBUCK) gCursor[i1] = excl + a; }
}

// rec32 = (dst&255)<<20 | (src*8+rel)
__global__ __launch_bounds__(256) void bucket_scatter(
    const int* __restrict__ src, const int* __restrict__ dst, const int* __restrict__ rel,
    int* __restrict__ gCursor, int* __restrict__ pairbuf) {
    __shared__ int hist[NBUCK];
    int t = threadIdx.x;
    for (int i = t; i < NBUCK; i += 256) hist[i] = 0;
    __syncthreads();
    int base = blockIdx.x * CHUNK;
    #pragma unroll
    for (int j = 0; j < CHUNK / 256; ++j) {
        int e = base + j * 256 + t;
        if (e < NE) atomicAdd(&hist[dst[e] >> BSHIFT], 1);
    }
    __syncthreads();
    for (int i = t; i < NBUCK; i += 256) {
        int v = hist[i];
        hist[i] = v ? atomicAdd(&gCursor[i], v) : 0;
    }
    __syncthreads();
    #pragma unroll
    for (int j = 0; j < CHUNK / 256; ++j) {
        int e = base + j * 256 + t;
        if (e < NE) {
            int d = dst[e];
            int b = d >> BSHIFT;
            int rec = ((d & 255) << 20) | (src[e] * 8 + rel[e]);
            int pos = atomicAdd(&hist[b], 1);
            pairbuf[pos] = rec;
        }
    }
}

__global__ __launch_bounds__(256) void exact_place(
    const int* __restrict__ bucketOff, const int* __restrict__ pairbuf,
    int* __restrict__ offsets, int2* __restrict__ rec2) {
    __shared__ int hist[256];
    __shared__ int tsum[256];
    int b = blockIdx.x, t = threadIdx.x;
    int start = bucketOff[b], cnt = bucketOff[b + 1] - start;
    hist[t] = 0;
    __syncthreads();
    for (int i = t; i < cnt; i += 256) atomicAdd(&hist[pairbuf[start + i] >> 20], 1);
    __syncthreads();
    int own = hist[t];
    tsum[t] = own;
    __syncthreads();
    for (int st = 1; st < 256; st <<= 1) {
        int y = (t >= st) ? tsum[t - st] : 0;
        __syncthreads();
        tsum[t] += y;
        __syncthreads();
    }
    int excl = start + tsum[t] - own;
    int node = b * 256 + t;
    if (node <= NN) offsets[node] = excl;
    __syncthreads();
    hist[t] = excl;
    __syncthreads();
    for (int i = t; i < cnt; i += 256) {
        int rec = pairbuf[start + i];
        int pos = atomicAdd(&hist[rec >> 20], 1);
        int sr = rec & 0xFFFFF;
        rec2[pos] = make_int2((sr >> 3) * 64 + (sr & 7) * 4,            // elr float index
                              (sr & 7) * (NN * 64) + (sr >> 3) * 64);   // projR element index
    }
}

__global__ __launch_bounds__(256) void agg(
    const int* __restrict__ offsets, const int2* __restrict__ rec2,
    const float* __restrict__ elr, const bf16* __restrict__ projR,
    const float* __restrict__ bias, float* __restrict__ out) {
    __shared__ float s_alpha[4][64][4];
    __shared__ int   s_pidx[4][64];
    __shared__ float s_er[4][32];
    int wv = threadIdx.x >> 6, lane = threadIdx.x & 63;
    int d = blockIdx.x * 4 + wv;
    if (d >= NN) return;
    int off = offsets[d], end = offsets[d + 1];
    int deg = end - off;

    if (lane < 32) s_er[wv][lane] = elr[d * 64 + 32 + lane];
    __builtin_amdgcn_wave_barrier();
    asm volatile("s_waitcnt lgkmcnt(0)" ::: "memory");

    if (deg == 0) {
        if (lane < 32) {
            float2 bb = *(const float2*)&bias[lane * 2];
            *(float2*)&out[d * 64 + lane * 2] = bb;
        }
    } else if (deg <= 64) {
        // pass A: one edge per lane; one int2 load; exp once; stash alpha + pidx in LDS
        int i = off + lane;
        float e0 = 0.f, e1 = 0.f, e2 = 0.f, e3 = 0.f;
        int pidx = 0;
        if (i < end) {
            int2 rv = rec2[i];
            pidx = rv.y;
            float4 el4 = *(const float4*)&elr[rv.x];
            int erb = rv.x & 63;          // r*4
            float x;
            x = el4.x + s_er[wv][erb + 0]; x = x > 0.f ? x : LEAKY * x; e0 = __expf(x);
            x = el4.y + s_er[wv][erb + 1]; x = x > 0.f ? x : LEAKY * x; e1 = __expf(x);
            x = el4.z + s_er[wv][erb + 2]; x = x > 0.f ? x : LEAKY * x; e2 = __expf(x);
            x = el4.w + s_er[wv][erb + 3]; x = x > 0.f ? x : LEAKY * x; e3 = __expf(x);
        }
        s_pidx[wv][lane] = pidx;
        *(float4*)&s_alpha[wv][lane][0] = make_float4(e0, e1, e2, e3);
        __builtin_amdgcn_wave_barrier();
        asm volatile("s_waitcnt lgkmcnt(0)" ::: "memory");

        // pass B: paired edges. half-wave hl handles edge j+hl; lane covers cols 2c,2c+1.
        int col2 = (lane & 31) * 2;
        int hl = lane >> 5;
        int h2 = (lane & 31) >> 3;        // head of both cols
        float acc0 = 0.f, acc1 = 0.f, dsum = 0.f;
        int j = 0;
        for (; j + 8 <= deg; j += 8) {
            unsigned uu[4];
            #pragma unroll
            for (int p = 0; p < 4; ++p) {
                int myp = s_pidx[wv][j + 2 * p + hl];
                uu[p] = *(const unsigned*)&projR[myp + col2];
            }
            #pragma unroll
            for (int p = 0; p < 4; ++p) {
                float a_self = s_alpha[wv][j + 2 * p + hl][h2];
                float a_oth  = s_alpha[wv][j + 2 * p + 1 - hl][h2];
                unsigned uo = __shfl_xor((int)uu[p], 32);
                acc0 = fmaf(a_self, bflo(uu[p]), acc0);
                acc1 = fmaf(a_self, bfhi(uu[p]), acc1);
                acc0 = fmaf(a_oth, bflo(uo), acc0);
                acc1 = fmaf(a_oth, bfhi(uo), acc1);
                dsum += a_self + a_oth;
            }
        }
        for (; j + 2 <= deg; j += 2) {
            int myp = s_pidx[wv][j + hl];
            unsigned u = *(const unsigned*)&projR[myp + col2];
            float a_self = s_alpha[wv][j + hl][h2];
            float a_oth  = s_alpha[wv][j + 1 - hl][h2];
            unsigned uo = __shfl_xor((int)u, 32);
            acc0 = fmaf(a_self, bflo(u), acc0);
            acc1 = fmaf(a_self, bfhi(u), acc1);
            acc0 = fmaf(a_oth, bflo(uo), acc0);
            acc1 = fmaf(a_oth, bfhi(uo), acc1);
            dsum += a_self + a_oth;
        }
        if (j < deg) {                    // odd tail: both halves same edge (no shuffle)
            int myp = s_pidx[wv][j];
            unsigned u = *(const unsigned*)&projR[myp + col2];
            float a = s_alpha[wv][j][h2];
            acc0 = fmaf(a, bflo(u), acc0);
            acc1 = fmaf(a, bfhi(u), acc1);
            dsum += a;
        }
        if (lane < 32) {
            float inv = 1.0f / dsum;
            float2 bb = *(const float2*)&bias[col2];
            float2 o;
            o.x = acc0 * inv + bb.x;
            o.y = acc1 * inv + bb.y;
            *(float2*)&out[d * 64 + col2] = o;
        }
    } else {
        // slow path (deg > 64): two-pass recompute (rare)
        int c = lane, h = c >> 4;
        float dsum0 = 0.f, dsum1 = 0.f, dsum2 = 0.f, dsum3 = 0.f;
        for (int i = off + lane; i < end; i += 64) {
            int2 rv = rec2[i];
            float4 el4 = *(const float4*)&elr[rv.x];
            int erb = rv.x & 63;
            float x;
            x = el4.x + s_er[wv][erb + 0]; x = x > 0.f ? x : LEAKY * x; dsum0 += __expf(x);
            x = el4.y + s_er[wv][erb + 1]; x = x > 0.f ? x : LEAKY * x; dsum1 += __expf(x);
            x = el4.z + s_er[wv][erb + 2]; x = x > 0.f ? x : LEAKY * x; dsum2 += __expf(x);
            x = el4.w + s_er[wv][erb + 3]; x = x > 0.f ? x : LEAKY * x; dsum3 += __expf(x);
        }
        #pragma unroll
        for (int m = 32; m; m >>= 1) {
            dsum0 += __shfl_xor(dsum0, m, 64);
            dsum1 += __shfl_xor(dsum1, m, 64);
            dsum2 += __shfl_xor(dsum2, m, 64);
            dsum3 += __shfl_xor(dsum3, m, 64);
        }
        float dh = (h == 0) ? dsum0 : (h == 1) ? dsum1 : (h == 2) ? dsum2 : dsum3;
        float rd = 1.0f / dh;
        float acc = 0.f;
        for (int i = off; i < end; ++i) {
            int2 rv = rec2[i];            // wave-uniform -> broadcast
            float x = elr[rv.x + h] + s_er[wv][(rv.x & 63) + h];
            x = x > 0.f ? x : LEAKY * x;
            acc = fmaf(__expf(x) * rd, __bfloat162float(projR[rv.y + c]), acc);
        }
        out[d * 64 + c] = acc + bias[c];
    }
}

extern "C" void kernel_launch(void* const* d_in, const int* in_sizes, int n_in,
                              void* d_out, int out_size, void* d_ws, size_t ws_size,
                              hipStream_t stream) {
    const float* inputs = (const float*)d_in[0];
    const float* convw  = (const float*)d_in[1];
    const float* attn_l = (const float*)d_in[2];
    const float* attn_r = (const float*)d_in[3];
    const float* h_bias = (const float*)d_in[4];
    const int*   src    = (const int*)d_in[5];
    const int*   dst    = (const int*)d_in[6];
    const int*   rel    = (const int*)d_in[7];
    float* out = (float*)d_out;

    char* ws = (char*)d_ws;
    size_t o = 0;
    bf16* projR = (bf16*)(ws + o);  o += 102400000ull;   // [8][NN][64]
    float* elr  = (float*)(ws + o); o += 25600000ull;
    short* wxt2 = (short*)(ws + o); o += 147456;
    int* offsets     = (int*)(ws + o); o += 400128;
    int* bucketCount = (int*)(ws + o); o += 1600;
    int* bucketOff   = (int*)(ws + o); o += 1600;
    int* gCursor     = (int*)(ws + o); o += 1600;
    int* pairbuf     = (int*)(ws + o); o += 6400000ull;
    int2* rec2       = (int2*)(ws + o); o += 12800000ull;

    hipLaunchKernelGGL(build_wextT, dim3(290), dim3(256), 0, stream, convw, attn_l, attn_r, wxt2, bucketCount);
    hipLaunchKernelGGL(gemm_direct, dim3(NNP / 128), dim3(512), 0, stream, inputs, wxt2, projR, elr);
    hipLaunchKernelGGL(bucket_count, dim3(NBUCK), dim3(256), 0, stream, dst, bucketCount);
    hipLaunchKernelGGL(scan_buckets, dim3(1), dim3(256), 0, stream, bucketCount, bucketOff, gCursor);
    hipLaunchKernelGGL(bucket_scatter, dim3(NBUCK), dim3(256), 0, stream, src, dst, rel, gCursor, pairbuf);
    hipLaunchKernelGGL(exact_place, dim3(NBUCK), dim3(256), 0, stream, bucketOff, pairbuf, offsets, rec2);
    hipLaunchKernelGGL(agg, dim3(25000), dim3(256), 0, stream, offsets, rec2, elr, projR, h_bias, out);
}

// Round 11
// 150.729 us; speedup vs baseline: 1.2408x; 1.1741x over previous
//
#include <hip/hip_runtime.h>
#include <hip/hip_bf16.h>

// HET relational attention layer.
//  K1 build_wextT : W_ext fragment-major (gemm B-frag load = contiguous 1KB);
//                   blocks >= 288 zero gCursor.
//  K2 fused       : blocks < 782 : gemm (4 waves, 32 rows/wave, A via XOR-swizzled LDS,
//                   swapped-operand MFMA, C via swizzled LDS -> coalesced NONTEMPORAL 1KB
//                   stores; projR layout [rel][node][64]).
//                   blocks >= 782: bucket_scatter into FIXED regions (b*CAP), LDS hist +
//                   one global atomic per bucket per block. No count/scan kernels.
//  K3 exact_place : one block per bucket; per-node LDS hist+scan; offdeg[node]={start,deg};
//                   rec2[pos] = {elr_idx = s*64+r*4, pidx = r*NN*64+s*64}.
//  K4 agg         : 1 wave per dst node. Fast path deg<=64: pass A = int2 load + exp once
//                   -> LDS; pass B = paired edges (half-wave per edge, uint = 2 bf16 cols,
//                   shfl_xor(32) exchange).

#define NN 100000
#define NNP 100096            // 782*128
#define NE 1600000
#define NH 4
#define INF_ 128
#define DH 16
#define NCOL 576
#define LEAKY 0.2f
#define NBUCK 391
#define BSHIFT 8
#define CHUNK 4096
#define CAP 5120              // fixed bucket capacity (mean 4096, +16 sigma)
#define GEMM_BLOCKS 782

typedef __hip_bfloat16 bf16;
typedef __attribute__((ext_vector_type(8))) short bf16x8;
typedef __attribute__((ext_vector_type(4))) short bf16x4;
typedef __attribute__((ext_vector_type(4))) float f32x4;

static __device__ __forceinline__ short f2bs(float x) {
    bf16 b = __float2bfloat16(x);
    return *reinterpret_cast<short*>(&b);
}
static __device__ __forceinline__ float bflo(unsigned u) { return __uint_as_float(u << 16); }
static __device__ __forceinline__ float bfhi(unsigned u) { return __uint_as_float(u & 0xffff0000u); }

// Fragment-major W. Blocks >= 288: zero gCursor.
__global__ void build_wextT(const float* __restrict__ W, const float* __restrict__ al,
                            const float* __restrict__ ar, short* __restrict__ wxt2,
                            int* __restrict__ gCursor) {
    if (blockIdx.x >= 288) {
        int i = (blockIdx.x - 288) * 256 + threadIdx.x;
        if (i < NBUCK) gCursor[i] = 0;
        return;
    }
    int idx = blockIdx.x * 256 + threadIdx.x;
    int e = idx & 7, lane = (idx >> 3) & 63, ct = (idx >> 9) & 3, ks = (idx >> 11) & 3, cb = idx >> 13;
    int g = lane >> 4, r = lane & 15;
    int c = cb * 64 + ct * 16 + r;
    int k = ks * 32 + g * 8 + e;
    float v;
    if (c < 512) {
        int rr = c >> 6, rem = c & 63, h = rem >> 4, d = rem & 15;
        v = W[((rr * NH + h) * INF_ + k) * DH + d];
    } else {
        int rh = c - 512;
        const float* a = al;
        if (rh >= 32) { rh -= 32; a = ar; }
        int rr = rh >> 2, h = rh & 3;
        const float* wp = &W[((rr * NH + h) * INF_ + k) * DH];
        const float* ap = &a[(rr * NH + h) * DH];
        float s = 0.f;
        #pragma unroll
        for (int d = 0; d < DH; ++d) s += wp[d] * ap[d];
        v = s;
    }
    wxt2[idx] = f2bs(v);
}

// Fused: gemm (blocks < GEMM_BLOCKS) + bucket_scatter (rest). 256 threads.
__global__ __launch_bounds__(256) void gemm_fused(
    const float* __restrict__ A, const short* __restrict__ WxT2,
    bf16* __restrict__ projR, float* __restrict__ elr,
    const int* __restrict__ src, const int* __restrict__ dst, const int* __restrict__ rel,
    int* __restrict__ gCursor, int* __restrict__ pairbuf) {
    __shared__ short As[16384];          // 32 KB: A-tile / C-slices (gemm) or hist (scatter)
    int t = threadIdx.x;

    if (blockIdx.x >= GEMM_BLOCKS) {
        // ---- bucket_scatter into fixed regions ----
        int* hist = (int*)As;
        int blk = blockIdx.x - GEMM_BLOCKS;
        for (int i = t; i < NBUCK; i += 256) hist[i] = 0;
        __syncthreads();
        int base = blk * CHUNK;
        #pragma unroll
        for (int j = 0; j < CHUNK / 256; ++j) {
            int e = base + j * 256 + t;
            if (e < NE) atomicAdd(&hist[dst[e] >> BSHIFT], 1);
        }
        __syncthreads();
        for (int i = t; i < NBUCK; i += 256) {
            int v = hist[i];
            hist[i] = v ? (i * CAP + atomicAdd(&gCursor[i], v)) : 0;
        }
        __syncthreads();
        #pragma unroll
        for (int j = 0; j < CHUNK / 256; ++j) {
            int e = base + j * 256 + t;
            if (e < NE) {
                int d = dst[e];
                int b = d >> BSHIFT;
                int rec = ((d & 255) << 20) | (src[e] * 8 + rel[e]);
                int pos = atomicAdd(&hist[b], 1);
                pairbuf[pos] = rec;
            }
        }
        return;
    }

    // ---- gemm: 4 waves, 32 rows/wave, 128 rows/block, all 576 cols ----
    int wv = t >> 6, lane = t & 63;
    int n0 = blockIdx.x * 128;
    int g = lane >> 4, r = lane & 15;

    #pragma unroll
    for (int j = 0; j < 8; ++j) {
        int i = j * 256 + t;
        int row = i >> 4, c8 = i & 15;
        int gr = n0 + row;
        bf16x8 v;
        if (gr < NN) {
            float4 f0 = *(const float4*)&A[gr * INF_ + c8 * 8];
            float4 f1 = *(const float4*)&A[gr * INF_ + c8 * 8 + 4];
            v[0] = f2bs(f0.x); v[1] = f2bs(f0.y); v[2] = f2bs(f0.z); v[3] = f2bs(f0.w);
            v[4] = f2bs(f1.x); v[5] = f2bs(f1.y); v[6] = f2bs(f1.z); v[7] = f2bs(f1.w);
        } else {
            v = (bf16x8)(short)0;
        }
        *(bf16x8*)&As[(row * 16 + (c8 ^ (row & 7))) * 8] = v;
    }
    __syncthreads();

    bf16x8 afr[2][4];
    #pragma unroll
    for (int nt = 0; nt < 2; ++nt) {
        int row = wv * 32 + nt * 16 + r;
        #pragma unroll
        for (int ks = 0; ks < 4; ++ks)
            afr[nt][ks] = *(const bf16x8*)&As[(row * 16 + ((ks * 4 + g) ^ (r & 7))) * 8];
    }
    __syncthreads();                      // A-tile dead; reuse as C-stage
    short* Csh = &As[wv * 4096];          // per-wave 8 KB slice
    float* Csf = (float*)Csh;
    int n0w = n0 + wv * 32;

    for (int cb = 0; cb < 9; ++cb) {
        f32x4 acc[2][4] = {};
        #pragma unroll
        for (int ks = 0; ks < 4; ++ks) {
            #pragma unroll
            for (int ct = 0; ct < 4; ++ct) {
                bf16x8 b = *(const bf16x8*)&WxT2[(((cb * 4 + ks) * 4 + ct) * 64 + lane) * 8];
                acc[0][ct] = __builtin_amdgcn_mfma_f32_16x16x32_bf16(b, afr[0][ks], acc[0][ct], 0, 0, 0);
                acc[1][ct] = __builtin_amdgcn_mfma_f32_16x16x32_bf16(b, afr[1][ks], acc[1][ct], 0, 0, 0);
            }
        }
        // lane(g,r), reg q: row = n0w + nt*16 + r, col = cb*64 + ct*16 + g*4 + q.
        if (cb < 8) {
            #pragma unroll
            for (int nt = 0; nt < 2; ++nt) {
                int rr = nt * 16 + r;
                #pragma unroll
                for (int ct = 0; ct < 4; ++ct) {
                    bf16x4 p;
                    p[0] = f2bs(acc[nt][ct][0]); p[1] = f2bs(acc[nt][ct][1]);
                    p[2] = f2bs(acc[nt][ct][2]); p[3] = f2bs(acc[nt][ct][3]);
                    *(bf16x4*)&Csh[rr * 64 + (((ct * 4 + g) ^ ((rr & 7) << 1)) << 2)] = p;
                }
            }
            __builtin_amdgcn_wave_barrier();
            size_t base = ((size_t)cb * NN + n0w) * 64;
            #pragma unroll
            for (int q = 0; q < 4; ++q) {
                int rr = (lane >> 3) + q * 8;
                if (n0w + rr < NN) {
                    bf16x8 vv = *(const bf16x8*)&Csh[rr * 64 + (((lane & 7) ^ (rr & 7)) << 3)];
                    __builtin_nontemporal_store(vv, (bf16x8*)&((short*)projR)[base + q * 512 + lane * 8]);
                }
            }
            __builtin_amdgcn_wave_barrier();
        } else {
            #pragma unroll
            for (int nt = 0; nt < 2; ++nt) {
                int rr = nt * 16 + r;
                #pragma unroll
                for (int ct = 0; ct < 4; ++ct)
                    *(f32x4*)&Csf[rr * 64 + (((ct * 4 + g) ^ ((rr & 7) << 1)) << 2)] = acc[nt][ct];
            }
            __builtin_amdgcn_wave_barrier();
            #pragma unroll
            for (int q = 0; q < 8; ++q) {
                int rr = (lane >> 4) + q * 4;
                if (n0w + rr < NN) {
                    f32x4 vv = *(const f32x4*)&Csf[rr * 64 + (((lane & 15) ^ ((rr & 7) << 1)) << 2)];
                    __builtin_nontemporal_store(vv, (f32x4*)&elr[(size_t)n0w * 64 + q * 256 + lane * 4]);
                }
            }
        }
    }
}

// One block per bucket: per-node hist -> scan -> offdeg {start,deg} + rec2 exact scatter.
__global__ __launch_bounds__(256) void exact_place(
    const int* __restrict__ gCursor, const int* __restrict__ pairbuf,
    int2* __restrict__ offdeg, int2* __restrict__ rec2) {
    __shared__ int hist[256];
    __shared__ int tsum[256];
    int b = blockIdx.x, t = threadIdx.x;
    int start = b * CAP, cnt = gCursor[b];
    hist[t] = 0;
    __syncthreads();
    for (int i = t; i < cnt; i += 256) atomicAdd(&hist[pairbuf[start + i] >> 20], 1);
    __syncthreads();
    int own = hist[t];
    tsum[t] = own;
    __syncthreads();
    for (int st = 1; st < 256; st <<= 1) {
        int y = (t >= st) ? tsum[t - st] : 0;
        __syncthreads();
        tsum[t] += y;
        __syncthreads();
    }
    int excl = start + tsum[t] - own;
    int node = b * 256 + t;
    if (node < NN) offdeg[node] = make_int2(excl, own);
    __syncthreads();
    hist[t] = excl;
    __syncthreads();
    for (int i = t; i < cnt; i += 256) {
        int rec = pairbuf[start + i];
        int pos = atomicAdd(&hist[rec >> 20], 1);
        int sr = rec & 0xFFFFF;
        rec2[pos] = make_int2((sr >> 3) * 64 + (sr & 7) * 4,            // elr float index
                              (sr & 7) * (NN * 64) + (sr >> 3) * 64);   // projR element index
    }
}

__global__ __launch_bounds__(256) void agg(
    const int2* __restrict__ offdeg, const int2* __restrict__ rec2,
    const float* __restrict__ elr, const bf16* __restrict__ projR,
    const float* __restrict__ bias, float* __restrict__ out) {
    __shared__ float s_alpha[4][64][4];
    __shared__ int   s_pidx[4][64];
    __shared__ float s_er[4][32];
    int wv = threadIdx.x >> 6, lane = threadIdx.x & 63;
    int d = blockIdx.x * 4 + wv;
    if (d >= NN) return;
    int2 od = offdeg[d];
    int off = od.x, deg = od.y;
    int end = off + deg;

    if (lane < 32) s_er[wv][lane] = elr[d * 64 + 32 + lane];
    __builtin_amdgcn_wave_barrier();
    asm volatile("s_waitcnt lgkmcnt(0)" ::: "memory");

    if (deg == 0) {
        if (lane < 32) {
            float2 bb = *(const float2*)&bias[lane * 2];
            *(float2*)&out[d * 64 + lane * 2] = bb;
        }
    } else if (deg <= 64) {
        int i = off + lane;
        float e0 = 0.f, e1 = 0.f, e2 = 0.f, e3 = 0.f;
        int pidx = 0;
        if (i < end) {
            int2 rv = rec2[i];
            pidx = rv.y;
            float4 el4 = *(const float4*)&elr[rv.x];
            int erb = rv.x & 63;          // r*4
            float x;
            x = el4.x + s_er[wv][erb + 0]; x = x > 0.f ? x : LEAKY * x; e0 = __expf(x);
            x = el4.y + s_er[wv][erb + 1]; x = x > 0.f ? x : LEAKY * x; e1 = __expf(x);
            x = el4.z + s_er[wv][erb + 2]; x = x > 0.f ? x : LEAKY * x; e2 = __expf(x);
            x = el4.w + s_er[wv][erb + 3]; x = x > 0.f ? x : LEAKY * x; e3 = __expf(x);
        }
        s_pidx[wv][lane] = pidx;
        *(float4*)&s_alpha[wv][lane][0] = make_float4(e0, e1, e2, e3);
        __builtin_amdgcn_wave_barrier();
        asm volatile("s_waitcnt lgkmcnt(0)" ::: "memory");

        int col2 = (lane & 31) * 2;
        int hl = lane >> 5;
        int h2 = (lane & 31) >> 3;
        float acc0 = 0.f, acc1 = 0.f, dsum = 0.f;
        int j = 0;
        for (; j + 8 <= deg; j += 8) {
            unsigned uu[4];
            #pragma unroll
            for (int p = 0; p < 4; ++p) {
                int myp = s_pidx[wv][j + 2 * p + hl];
                uu[p] = *(const unsigned*)&projR[myp + col2];
            }
            #pragma unroll
            for (int p = 0; p < 4; ++p) {
                float a_self = s_alpha[wv][j + 2 * p + hl][h2];
                float a_oth  = s_alpha[wv][j + 2 * p + 1 - hl][h2];
                unsigned uo = __shfl_xor((int)uu[p], 32);
                acc0 = fmaf(a_self, bflo(uu[p]), acc0);
                acc1 = fmaf(a_self, bfhi(uu[p]), acc1);
                acc0 = fmaf(a_oth, bflo(uo), acc0);
                acc1 = fmaf(a_oth, bfhi(uo), acc1);
                dsum += a_self + a_oth;
            }
        }
        for (; j + 2 <= deg; j += 2) {
            int myp = s_pidx[wv][j + hl];
            unsigned u = *(const unsigned*)&projR[myp + col2];
            float a_self = s_alpha[wv][j + hl][h2];
            float a_oth  = s_alpha[wv][j + 1 - hl][h2];
            unsigned uo = __shfl_xor((int)u, 32);
            acc0 = fmaf(a_self, bflo(u), acc0);
            acc1 = fmaf(a_self, bfhi(u), acc1);
            acc0 = fmaf(a_oth, bflo(uo), acc0);
            acc1 = fmaf(a_oth, bfhi(uo), acc1);
            dsum += a_self + a_oth;
        }
        if (j < deg) {
            int myp = s_pidx[wv][j];
            unsigned u = *(const unsigned*)&projR[myp + col2];
            float a = s_alpha[wv][j][h2];
            acc0 = fmaf(a, bflo(u), acc0);
            acc1 = fmaf(a, bfhi(u), acc1);
            dsum += a;
        }
        if (lane < 32) {
            float inv = 1.0f / dsum;
            float2 bb = *(const float2*)&bias[col2];
            float2 o;
            o.x = acc0 * inv + bb.x;
            o.y = acc1 * inv + bb.y;
            *(float2*)&out[d * 64 + col2] = o;
        }
    } else {
        int c = lane, h = c >> 4;
        float dsum0 = 0.f, dsum1 = 0.f, dsum2 = 0.f, dsum3 = 0.f;
        for (int i = off + lane; i < end; i += 64) {
            int2 rv = rec2[i];
            float4 el4 = *(const float4*)&elr[rv.x];
            int erb = rv.x & 63;
            float x;
            x = el4.x + s_er[wv][erb + 0]; x = x > 0.f ? x : LEAKY * x; dsum0 += __expf(x);
            x = el4.y + s_er[wv][erb + 1]; x = x > 0.f ? x : LEAKY * x; dsum1 += __expf(x);
            x = el4.z + s_er[wv][erb + 2]; x = x > 0.f ? x : LEAKY * x; dsum2 += __expf(x);
            x = el4.w + s_er[wv][erb + 3]; x = x > 0.f ? x : LEAKY * x; dsum3 += __expf(x);
        }
        #pragma unroll
        for (int m = 32; m; m >>= 1) {
            dsum0 += __shfl_xor(dsum0, m, 64);
            dsum1 += __shfl_xor(dsum1, m, 64);
            dsum2 += __shfl_xor(dsum2, m, 64);
            dsum3 += __shfl_xor(dsum3, m, 64);
        }
        float dh = (h == 0) ? dsum0 : (h == 1) ? dsum1 : (h == 2) ? dsum2 : dsum3;
        float rd = 1.0f / dh;
        float acc = 0.f;
        for (int i = off; i < end; ++i) {
            int2 rv = rec2[i];
            float x = elr[rv.x + h] + s_er[wv][(rv.x & 63) + h];
            x = x > 0.f ? x : LEAKY * x;
            acc = fmaf(__expf(x) * rd, __bfloat162float(projR[rv.y + c]), acc);
        }
        out[d * 64 + c] = acc + bias[c];
    }
}

extern "C" void kernel_launch(void* const* d_in, const int* in_sizes, int n_in,
                              void* d_out, int out_size, void* d_ws, size_t ws_size,
                              hipStream_t stream) {
    const float* inputs = (const float*)d_in[0];
    const float* convw  = (const float*)d_in[1];
    const float* attn_l = (const float*)d_in[2];
    const float* attn_r = (const float*)d_in[3];
    const float* h_bias = (const float*)d_in[4];
    const int*   src    = (const int*)d_in[5];
    const int*   dst    = (const int*)d_in[6];
    const int*   rel    = (const int*)d_in[7];
    float* out = (float*)d_out;

    char* ws = (char*)d_ws;
    size_t o = 0;
    bf16* projR = (bf16*)(ws + o);  o += 102400000ull;    // [8][NN][64]
    float* elr  = (float*)(ws + o); o += 25600000ull;
    short* wxt2 = (short*)(ws + o); o += 147456;
    int2* offdeg = (int2*)(ws + o); o += 800768;          // NN int2
    int* gCursor = (int*)(ws + o);  o += 2048;
    int* pairbuf = (int*)(ws + o);  o += (size_t)NBUCK * CAP * 4;   //  8,007,680
    int2* rec2   = (int2*)(ws + o); o += (size_t)NBUCK * CAP * 8;   // 16,015,360

    hipLaunchKernelGGL(build_wextT, dim3(290), dim3(256), 0, stream, convw, attn_l, attn_r, wxt2, gCursor);
    hipLaunchKernelGGL(gemm_fused, dim3(GEMM_BLOCKS + NBUCK), dim3(256), 0, stream,
                       inputs, wxt2, projR, elr, src, dst, rel, gCursor, pairbuf);
    hipLaunchKernelGGL(exact_place, dim3(NBUCK), dim3(256), 0, stream, gCursor, pairbuf, offdeg, rec2);
    hipLaunchKernelGGL(agg, dim3(25000), dim3(256), 0, stream, offdeg, rec2, elr, projR, h_bias, out);
}